// Round 1
// baseline (2073.823 us; speedup 1.0000x reference)
//
#include <hip/hip_runtime.h>

// VanillaRNN: h_{t+1} = tanh(W_hx x_t + W_hh h_t + b_h), 1024 steps, H=512, B=256.
// Design: one batch column per workgroup (256 wgs = 256 CUs), NO inter-wg sync.
// W_hh held f16 per-CU: 44 chunks in VGPRs + 13 chunks in LDS + 7 chunks streamed
// from a repacked ws buffer (prefetchable: W static). h double-buffered f16 in LDS
// (broadcast reads). K-dim math via v_dot2_f32_f16 (2 MAC/lane/cyc).

#define T_SEQ      1024
#define HID        512
#define NCLS       10
#define NTHREADS   512         // 8 waves; thread = output row
#define NCHUNK     64          // 64 chunks x 8 halfs = 512 k
#define REG_CHUNKS 44          // k in [0,352) in VGPRs (176 regs/thread)
#define LDS_CHUNKS 13          // k in [352,456) in LDS (104 KB)
#define STREAM_CHUNKS 7        // k in [456,512) streamed from ws each step

typedef _Float16 half2_t __attribute__((ext_vector_type(2)));

__device__ __forceinline__ unsigned int pack2(float a, float b) {
    half2_t h = {(_Float16)a, (_Float16)b};
    return __builtin_bit_cast(unsigned int, h);
}

__device__ __forceinline__ uint4 pack8(float4 a, float4 b) {
    uint4 r;
    r.x = pack2(a.x, a.y); r.y = pack2(a.z, a.w);
    r.z = pack2(b.x, b.y); r.w = pack2(b.z, b.w);
    return r;
}

__device__ __forceinline__ float dot2(unsigned int w, unsigned int h, float acc) {
#if __has_builtin(__builtin_amdgcn_fdot2)
    return __builtin_amdgcn_fdot2(__builtin_bit_cast(half2_t, w),
                                  __builtin_bit_cast(half2_t, h), acc, false);
#else
    half2_t wv = __builtin_bit_cast(half2_t, w), hv = __builtin_bit_cast(half2_t, h);
    return acc + (float)wv.x * (float)hv.x + (float)wv.y * (float)hv.y;
#endif
}

__device__ __forceinline__ float chunk_dot(uint4 w8, uint4 h8, float acc) {
    acc = dot2(w8.x, h8.x, acc);
    acc = dot2(w8.y, h8.y, acc);
    acc = dot2(w8.z, h8.z, acc);
    acc = dot2(w8.w, h8.w, acc);
    return acc;
}

// Repack stream chunks (k in [456,512)) of W_hh into ws, layout [chunk][row] so
// the main loop's per-step global loads are perfectly coalesced (lane = row).
__global__ void pack_ws(const float* __restrict__ W_hh, uint4* __restrict__ Ws) {
    int idx = blockIdx.x * blockDim.x + threadIdx.x;   // 0 .. 7*512-1
    if (idx >= STREAM_CHUNKS * HID) return;
    int j = idx >> 9;          // stream chunk 0..6
    int r = idx & 511;         // row
    int c = REG_CHUNKS + LDS_CHUNKS + j;               // global chunk 57..63
    const float4* wrow = (const float4*)(W_hh + (size_t)r * HID);
    Ws[j * HID + r] = pack8(wrow[2 * c], wrow[2 * c + 1]);
}

template <bool USE_WS>
__global__ __launch_bounds__(NTHREADS, 2) void rnn_persist(
    const float* __restrict__ x, const float* __restrict__ h_init,
    const float* __restrict__ W_hx, const float* __restrict__ W_hh,
    const float* __restrict__ b_h, const float* __restrict__ W_ph,
    const float* __restrict__ b_p, const uint4* __restrict__ Ws,
    float* __restrict__ out)
{
    __shared__ uint4 Wl[LDS_CHUNKS * HID];   // 104 KB: W chunks 44..56, [chunk][row]
    __shared__ uint4 hbuf[2][NCHUNK];        // 2 KB: h double buffer, f16
    __shared__ float x_s[T_SEQ];             // 4 KB: this column's inputs

    const int tid = threadIdx.x;             // row r
    const int b   = blockIdx.x;              // batch column

    // Stage x row (coalesced).
    for (int i = tid; i < T_SEQ; i += NTHREADS) x_s[i] = x[(size_t)b * T_SEQ + i];

    const float whx = W_hx[tid];
    const float bh  = b_h[tid];

    // h0 = h_init broadcast over batch (f16 path; h_init is zeros anyway).
    ((_Float16*)hbuf[0])[tid] = (_Float16)h_init[tid];

    // Load this row's W into VGPRs (chunks 0..43) and LDS (chunks 44..56).
    const float4* wrow = (const float4*)(W_hh + (size_t)tid * HID);
    unsigned int wreg[REG_CHUNKS * 4];
    #pragma unroll
    for (int c = 0; c < REG_CHUNKS; ++c) {
        float4 a = wrow[2 * c], q = wrow[2 * c + 1];
        wreg[4 * c + 0] = pack2(a.x, a.y);
        wreg[4 * c + 1] = pack2(a.z, a.w);
        wreg[4 * c + 2] = pack2(q.x, q.y);
        wreg[4 * c + 3] = pack2(q.z, q.w);
    }
    for (int c = 0; c < LDS_CHUNKS; ++c) {
        int gc = REG_CHUNKS + c;
        Wl[c * HID + tid] = pack8(wrow[2 * gc], wrow[2 * gc + 1]);
    }
    __syncthreads();

    float hval = 0.0f;
    for (int t = 0; t < T_SEQ; ++t) {
        const int p = t & 1;

        // Stream W chunks for THIS step: no dependence on h, issued before the
        // barrier so the L2 latency hides under it and under the dot chain.
        uint4 sv[STREAM_CHUNKS];
        if (USE_WS) {
            #pragma unroll
            for (int j = 0; j < STREAM_CHUNKS; ++j) sv[j] = Ws[j * HID + tid];
        } else {
            #pragma unroll
            for (int j = 0; j < STREAM_CHUNKS; ++j) {
                int gc = REG_CHUNKS + LDS_CHUNKS + j;
                sv[j] = pack8(wrow[2 * gc], wrow[2 * gc + 1]);
            }
        }

        // Barrier separates prev step's hbuf reads from this step's writes
        // (double buffer => one barrier per step is sufficient).
        __syncthreads();

        float acc = whx * x_s[t] + bh;
        const uint4* hb = hbuf[p];

        #pragma unroll
        for (int c = 0; c < REG_CHUNKS; ++c) {
            uint4 h8 = hb[c];                       // wave-uniform: LDS broadcast
            acc = dot2(wreg[4 * c + 0], h8.x, acc);
            acc = dot2(wreg[4 * c + 1], h8.y, acc);
            acc = dot2(wreg[4 * c + 2], h8.z, acc);
            acc = dot2(wreg[4 * c + 3], h8.w, acc);
        }
        #pragma unroll
        for (int c = 0; c < LDS_CHUNKS; ++c) {
            uint4 h8 = hb[REG_CHUNKS + c];
            uint4 w8 = Wl[c * HID + tid];           // lanes contiguous: conflict-free
            acc = chunk_dot(w8, h8, acc);
        }
        #pragma unroll
        for (int j = 0; j < STREAM_CHUNKS; ++j) {
            uint4 h8 = hb[REG_CHUNKS + LDS_CHUNKS + j];
            acc = chunk_dot(sv[j], h8, acc);
        }

        // tanh(a) = 1 - 2/(e^{2a}+1)  (safe at +/-inf of exp)
        hval = 1.0f - 2.0f / (__expf(2.0f * acc) + 1.0f);
        ((_Float16*)hbuf[1 - p])[tid] = (_Float16)hval;
    }

    // Epilogue: p = W_ph @ h_last + b_p for this column (reuse x_s for f32 h).
    __syncthreads();
    x_s[tid] = hval;
    __syncthreads();

    const int w = tid >> 6, lane = tid & 63;
    for (int c = w; c < NCLS; c += 8) {
        float s = 0.0f;
        #pragma unroll
        for (int j = 0; j < 8; ++j) {
            int r = lane + 64 * j;
            s += W_ph[c * HID + r] * x_s[r];
        }
        #pragma unroll
        for (int off = 32; off; off >>= 1) s += __shfl_down(s, off, 64);
        if (lane == 0) out[b * NCLS + c] = s + b_p[c];
    }
}

extern "C" void kernel_launch(void* const* d_in, const int* in_sizes, int n_in,
                              void* d_out, int out_size, void* d_ws, size_t ws_size,
                              hipStream_t stream) {
    const float* x      = (const float*)d_in[0];
    const float* h_init = (const float*)d_in[1];
    const float* W_hx   = (const float*)d_in[2];
    const float* W_hh   = (const float*)d_in[3];
    const float* b_h    = (const float*)d_in[4];
    const float* W_ph   = (const float*)d_in[5];
    const float* b_p    = (const float*)d_in[6];
    float* out = (float*)d_out;

    const int B = in_sizes[0] / T_SEQ;   // 256
    const size_t ws_need = (size_t)STREAM_CHUNKS * HID * sizeof(uint4);  // 56 KB

    if (d_ws && ws_size >= ws_need) {
        uint4* Ws = (uint4*)d_ws;
        pack_ws<<<(STREAM_CHUNKS * HID + 255) / 256, 256, 0, stream>>>(W_hh, Ws);
        rnn_persist<true><<<B, NTHREADS, 0, stream>>>(x, h_init, W_hx, W_hh, b_h,
                                                      W_ph, b_p, Ws, out);
    } else {
        rnn_persist<false><<<B, NTHREADS, 0, stream>>>(x, h_init, W_hx, W_hh, b_h,
                                                       W_ph, b_p, nullptr, out);
    }
}